// Round 6
// baseline (150.142 us; speedup 1.0000x reference)
//
#include <hip/hip_runtime.h>
#include <hip/hip_bf16.h>

typedef __attribute__((ext_vector_type(8))) __bf16 bf16x8;
typedef __attribute__((ext_vector_type(4))) float f32x4;
typedef unsigned long long ull;

#define NB 16
#define CIN 32
#define COUT 64
#define HW 224
#define HP 226                  // padded row slots
#define HWHW (HW * HW)          // 50176
#define CHW (CIN * HW * HW)     // 1605632
#define ROW_WORDS (HP * 16)     // 3616 dwords per LDS row (226 px * 16 dwords)
#define ROW_BYTES (HP * 64)     // 14464

__device__ __forceinline__ unsigned short f2bf(float f) {
    __hip_bfloat16 h = __float2bfloat16(f);
    return __builtin_bit_cast(unsigned short, h);
}

// ---- K1: weight OIHW fp32 -> wT[co][tap][cin] bf16 (64*9*32 = 18432) ----
__global__ void k_wxform(const float* __restrict__ w, unsigned short* __restrict__ wT) {
    int i = blockIdx.x * 256 + threadIdx.x;
    if (i >= COUT * 9 * CIN) return;
    int co = i / (9 * CIN);
    int r  = i % (9 * CIN);
    int tap = r / CIN;
    int c   = r % CIN;
    wT[i] = f2bf(w[(co * CIN + c) * 9 + tap]);
}

// Swizzled LDS dword index: row r3, px slot p (0..225), channel-pair c2 (0..15).
// 16B unit swizzle: unit' = (c2>>2) ^ (p&3)  -> uniform banks on ds_read_b128.
__device__ __forceinline__ int lds_widx(int r3, int p, int c2) {
    return r3 * ROW_WORDS + p * 16 + (((c2 >> 2) ^ (p & 3)) << 2) + (c2 & 3);
}

// ---- K2: fused conv. One block per (b,h); stage 3 x-rows in LDS (bf16,
// swizzled), then 4 waves x (64px x 64cout) MFMA, dense f32x4 stores. ----
__global__ __launch_bounds__(256, 3)
void k_fused(const float* __restrict__ x, const unsigned short* __restrict__ wT,
             const float* __restrict__ bias, float* __restrict__ out) {
    __shared__ __align__(16) unsigned int lds[3 * ROW_WORDS];   // 43392 B

    int bid = blockIdx.x;
    int wg  = (bid & 7) * 448 + (bid >> 3);   // XCD-chunked swizzle, 3584 = 8*448
    int b = wg / HW, h = wg % HW;
    int tid = threadIdx.x;

    // ---- stage: x[b, :, h-1..h+1, :] -> LDS [3][226][32] bf16, pads zeroed ----
    {
        int lane16 = tid & 15;
        int c2 = tid >> 4;                    // 0..15 (channel pair)
        int cc = c2 * 2;
        if (tid < 96) {                       // zero px-pad slots 0 and 225
            int r3 = tid / 32, t2 = tid % 32;
            int p = (t2 & 1) ? (HP - 1) : 0;
            int cz = t2 >> 1;
            lds[lds_widx(r3, p, cz)] = 0u;
        }
        const float* xb = x + (ull)b * CHW + (ull)cc * HWHW;
        #pragma unroll
        for (int r3 = 0; r3 < 3; ++r3) {
            int hy = h + r3 - 1;
            bool vrow = (hy >= 0) && (hy < HW);           // block-uniform
            const float* xr = xb + (ull)(vrow ? hy : 0) * HW;
            #pragma unroll
            for (int ch = 0; ch < 14; ++ch) {
                int px = ch * 16 + lane16;                // 0..223
                float f0 = 0.f, f1 = 0.f;
                if (vrow) { f0 = xr[px]; f1 = xr[HWHW + px]; }
                unsigned int pk = (unsigned)f2bf(f0) | ((unsigned)f2bf(f1) << 16);
                lds[lds_widx(r3, px + 1, c2)] = pk;
            }
        }
    }
    __syncthreads();

    // ---- compute ----
    int wave = tid >> 6, lane = tid & 63;
    int r15 = lane & 15;              // A-row (pixel local) / B-col (cout local)
    int q = lane >> 4;
    int chunk = q * 8;                // k sub-chunk (cin)

    int pc[4];
    #pragma unroll
    for (int pf = 0; pf < 4; ++pf) {
        int px = wave * 64 + pf * 16 + r15;
        pc[pf] = px < HW ? px : HW - 1;   // clamp masked tail (wave 3) into bounds
    }
    // byte offsets within an LDS row for each (pf, dw)
    int soff[4][3];
    #pragma unroll
    for (int pf = 0; pf < 4; ++pf)
        #pragma unroll
        for (int dw = 0; dw < 3; ++dw) {
            int slot = pc[pf] + dw;       // 0..225
            soff[pf][dw] = slot * 64 + ((q ^ (slot & 3)) << 4);
        }

    f32x4 acc[4][4];
    #pragma unroll
    for (int i = 0; i < 4; ++i)
        #pragma unroll
        for (int j = 0; j < 4; ++j) acc[i][j] = (f32x4){0.f, 0.f, 0.f, 0.f};

    const char* ldsc = reinterpret_cast<const char*>(lds);
    #pragma unroll
    for (int r3 = 0; r3 < 3; ++r3) {
        const char* lrow = ldsc + r3 * ROW_BYTES;
        #pragma unroll
        for (int dw = 0; dw < 3; ++dw) {
            int tap = r3 * 3 + dw;
            bf16x8 wf[4], xf[4];
            #pragma unroll
            for (int cf = 0; cf < 4; ++cf)
                wf[cf] = *reinterpret_cast<const bf16x8*>(wT + (cf * 16 + r15) * 288 + tap * 32 + chunk);
            #pragma unroll
            for (int pf = 0; pf < 4; ++pf)
                xf[pf] = *reinterpret_cast<const bf16x8*>(lrow + soff[pf][dw]);
            #pragma unroll
            for (int cf = 0; cf < 4; ++cf)
                #pragma unroll
                for (int pf = 0; pf < 4; ++pf)
                    acc[cf][pf] = __builtin_amdgcn_mfma_f32_16x16x32_bf16(xf[pf], wf[cf], acc[cf][pf], 0, 0, 0);
        }
    }

    // epilogue: D row = pixel = q*4+reg, col = cout = lane&15; normal stores
    // (16 lanes of a co-group fill full 64B lines -> L2 write-combines).
    #pragma unroll
    for (int cf = 0; cf < 4; ++cf) {
        int co = cf * 16 + r15;
        float bv = bias[co];
        float* orow = out + ((ull)(b * COUT + co) * HW + h) * HW;
        #pragma unroll
        for (int pf = 0; pf < 4; ++pf) {
            int pxb = wave * 64 + pf * 16;
            if (pxb < HW) {                  // frag fully valid or fully masked
                int px0 = pxb + q * 4;
                *reinterpret_cast<f32x4*>(orow + px0) = acc[cf][pf] + bv;
            }
        }
    }
}

// ---- fallback: naive direct fp32 conv (used only if ws too small) ----
__global__ void k_naive(const float* __restrict__ x, const float* __restrict__ w,
                        const float* __restrict__ bias, float* __restrict__ out, long long n) {
    long long i = (long long)blockIdx.x * 256 + threadIdx.x;
    if (i >= n) return;
    int wc = i % HW; long long t = i / HW;
    int h = t % HW; t /= HW;
    int co = t % COUT; int b = (int)(t / COUT);
    float s = bias[co];
    for (int c = 0; c < CIN; ++c)
        for (int dh = 0; dh < 3; ++dh) {
            int hy = h + dh - 1; if (hy < 0 || hy >= HW) continue;
            for (int dw = 0; dw < 3; ++dw) {
                int wx = wc + dw - 1; if (wx < 0 || wx >= HW) continue;
                s += x[(((long long)b * CIN + c) * HW + hy) * HW + wx] *
                     w[((co * CIN + c) * 3 + dh) * 3 + dw];
            }
        }
    out[i] = s;
}

extern "C" void kernel_launch(void* const* d_in, const int* in_sizes, int n_in,
                              void* d_out, int out_size, void* d_ws, size_t ws_size,
                              hipStream_t stream) {
    const float* x    = (const float*)d_in[0];
    const float* w    = (const float*)d_in[1];
    const float* bias = (const float*)d_in[2];
    float* out = (float*)d_out;

    if (ws_size < (size_t)(COUT * 9 * CIN * 2 + 1024)) {
        long long n = (long long)NB * COUT * HW * HW;
        k_naive<<<(int)((n + 255) / 256), 256, 0, stream>>>(x, w, bias, out, n);
        return;
    }
    unsigned short* wT = (unsigned short*)d_ws;

    k_wxform<<<72, 256, 0, stream>>>(w, wT);
    k_fused<<<NB * HW, 256, 0, stream>>>(x, wT, bias, out);
}